// Round 10
// baseline (138.395 us; speedup 1.0000x reference)
//
#include <hip/hip_runtime.h>
#include <stdint.h>

// QuantizedBatchNorm (k=8 fake-quant, training forward), NCHW = [64,256,56,56] f32.
//
// 3-kernel schedule (deterministic, no atomics), grid 256ch x 4 splits x 256 thr:
//  K1: read x (regular loads: allocate in L3 for K2 reuse) -> per-(c,s) partial
//      {sum, min, max}
//  K2: prologue = redundant S1; main = read x via NONTEMPORAL loads (x is dead
//      after K2 -> evict-first, so kq write-allocations hit dead-x ways instead
//      of unread x), fast fma quant level k (exact __fdiv_rn fallback near
//      floor boundaries), EXACT integer {sum k, sum k^2}, pack 4 levels ->
//      uint32, coalesced regular store (51 MB, L3-allocating for K3)
//  K3: prologue = S1+S2 (exact var from int sums -> per-channel y-LUT in LDS);
//      main = read kq via NONTEMPORAL loads (read-once), y = lut[k] float4/lane,
//      NT store (don't pollute L3).
// COALESCING RULE (round-6 lesson): lane i <-> slot i, unit stride across
// lanes, 16B/lane stores = full 64B lines.
// All ref-visible elementwise math uses __f*_rn sequences identical to numpy.

#define C_CH 256
#define P4 784                 // float4 per plane (HW/4)
#define PLANE_STRIDE 200704    // float4 stride between planes at fixed c (256*784)
#define NHW_F 200704.0f
#define NHW_D 200704.0
#define TOLB 1e-3f

typedef float natf4 __attribute__((ext_vector_type(4)));

__device__ __forceinline__ float fq(float x, float sc, float qn, float qx) {
  if (sc == 0.0f) return x;                                   // range==0 passthrough
  float cs = __fsub_rn(fminf(fmaxf(x, qn), qx), qn);
  float f  = floorf(__fadd_rn(__fdiv_rn(cs, sc), 0.5f));
  return __fadd_rn(__fmul_rn(f, sc), qn);
}

__device__ __forceinline__ void qparams(float amax, float& sc, float& qn, float& qx) {
  sc = __fdiv_rn(__fmul_rn(2.0f, amax), 255.0f);
  qn = __fmul_rn(-128.0f, sc);                                // nzp = round(127.5) = 128
  qx = __fmul_rn(127.0f, sc);
}

__device__ __forceinline__ float block_max(float v, float* buf4) {
  #pragma unroll
  for (int m = 1; m <= 32; m <<= 1) v = fmaxf(v, __shfl_xor(v, m, 64));
  if ((threadIdx.x & 63) == 0) buf4[threadIdx.x >> 6] = v;
  __syncthreads();
  float r = fmaxf(fmaxf(buf4[0], buf4[1]), fmaxf(buf4[2], buf4[3]));
  __syncthreads();
  return r;
}

// Fast quant level: q ~= (x - m - n1)/s1 via fma; exact __fdiv_rn ref-sequence
// fallback when within TOLB of a floor boundary (|fast-true| <= ~1e-4 << TOLB).
__device__ __forceinline__ uint32_t qlevel(float xv, float r2, float c2,
    float m, float s1, float n1, float x1) {
  float q = fmaf(xv, r2, c2);
  q = fminf(fmaxf(q, 0.0f), 255.0f);
  const float qh = __fadd_rn(q, 0.5f);
  float fl = floorf(qh);
  const float d = __fsub_rn(qh, fl);
  if (__builtin_expect(fminf(d, __fsub_rn(1.0f, d)) < TOLB, 0)) {
    const float tt = __fsub_rn(xv, m);
    const float cs = __fsub_rn(fminf(fmaxf(tt, n1), x1), n1);
    fl = floorf(__fadd_rn(__fdiv_rn(cs, s1), 0.5f));
  }
  return (uint32_t)fl;                                        // in [0,255]
}

// Redundant S1 (thread t <-> channel t; identical in every block).
struct S1Out { float meanc, tmax, tmin, s1, n1, x1; };

__device__ __forceinline__ void s1_compute(const float* __restrict__ psum,
    const float* __restrict__ pmin, const float* __restrict__ pmax,
    const float* __restrict__ run_mean, float* buf4, S1Out& o) {
  const int t = threadIdx.x;
  float sum = __fadd_rn(__fadd_rn(__fadd_rn(psum[4*t], psum[4*t+1]), psum[4*t+2]), psum[4*t+3]);
  float mn = fminf(fminf(pmin[4*t], pmin[4*t+1]), fminf(pmin[4*t+2], pmin[4*t+3]));
  float mx = fmaxf(fmaxf(pmax[4*t], pmax[4*t+1]), fmaxf(pmax[4*t+2], pmax[4*t+3]));
  const float new_mean = __fdiv_rn(sum, NHW_F);
  const float mp = __fadd_rn(__fmul_rn(0.875f, run_mean[t]), __fmul_rn(0.125f, new_mean));
  const float am = block_max(fabsf(mp), buf4);
  float scm, qnm, qxm; qparams(am, scm, qnm, qxm);
  o.meanc = fq(mp, scm, qnm, qxm);
  o.tmax = __fsub_rn(mx, o.meanc);   // (x - mean_c) monotone in x: extremes attained
  o.tmin = __fsub_rn(mn, o.meanc);
  const float a1 = block_max(fmaxf(fabsf(o.tmax), fabsf(o.tmin)), buf4);
  qparams(a1, o.s1, o.n1, o.x1);
}

// S2 body (thread t <-> channel t): exact var from integer sums -> LUT.
__device__ __forceinline__ void s2_and_lut(const S1Out& o,
    const uint32_t* __restrict__ pk, const uint32_t* __restrict__ pk2,
    const float* __restrict__ run_var, const float* __restrict__ weight,
    const float* __restrict__ bias, float* buf4, float* bc, float* lut, int c) {
  const int t = threadIdx.x;
  // sum(ctr^2) = s1^2 * (sum k^2 - 256 sum k + 16384*N)   (exact integers)
  const unsigned long long ssq = (unsigned long long)pk2[4*t] + pk2[4*t+1]
                               + pk2[4*t+2] + pk2[4*t+3];
  const unsigned int skc = pk[4*t] + pk[4*t+1] + pk[4*t+2] + pk[4*t+3];
  const double s1d = (double)o.s1;
  const double sum_ctr2 = s1d * s1d *
      ((double)ssq - 256.0 * (double)skc + 16384.0 * NHW_D);
  const float new_var = (float)(sum_ctr2 / NHW_D);
  const float vp = __fadd_rn(__fmul_rn(0.875f, run_var[t]), __fmul_rn(0.125f, new_var));
  const float av = block_max(fabsf(vp), buf4);
  float scv, qnv, qxv; qparams(av, scv, qnv, qxv);
  const float varc = fq(vp, scv, qnv, qxv);
  const float dp = __fsqrt_rn(__fadd_rn(varc, 1e-5f));
  const float ad = block_max(fabsf(dp), buf4);
  float scd, qnd, qxd; qparams(ad, scd, qnd, qxd);
  const float idc = fq(dp, scd, qnd, qxd);
  const float ctrmax = fq(o.tmax, o.s1, o.n1, o.x1);
  const float ctrmin = fq(o.tmin, o.s1, o.n1, o.x1);
  const float xpmax = __fdiv_rn(ctrmax, idc);
  const float xpmin = __fdiv_rn(ctrmin, idc);
  const float a3 = block_max(fmaxf(fabsf(xpmax), fabsf(xpmin)), buf4);
  float s3, n3, x3; qparams(a3, s3, n3, x3);
  const float xnmax = fq(xpmax, s3, n3, x3);
  const float xnmin = fq(xpmin, s3, n3, x3);
  const float wv = weight[t];
  const float aw = block_max(fabsf(wv), buf4);
  float scw, qnw, qxw; qparams(aw, scw, qnw, qxw);
  const float qw = fq(wv, scw, qnw, qxw);
  const float bv = bias[t];
  const float ab = block_max(fabsf(bv), buf4);
  float scb, qnb, qxb; qparams(ab, scb, qnb, qxb);
  const float qb = fq(bv, scb, qnb, qxb);                     // bias==0 -> passthrough
  const float e1 = __fadd_rn(__fmul_rn(qw, xnmax), qb);
  const float e2 = __fadd_rn(__fmul_rn(qw, xnmin), qb);
  const float a4 = block_max(fmaxf(fabsf(e1), fabsf(e2)), buf4);
  float s4, n4, x4q; qparams(a4, s4, n4, x4q);
  if (t == c) { bc[0] = idc; bc[1] = qw; bc[2] = qb; }
  __syncthreads();
  const float idc_c = bc[0], qw_c = bc[1], qb_c = bc[2];
  const float ctr_t = __fadd_rn(__fmul_rn((float)t, o.s1), o.n1);
  const float xn_t = fq(__fdiv_rn(ctr_t, idc_c), s3, n3, x3);
  lut[t] = fq(__fadd_rn(__fmul_rn(qw_c, xn_t), qb_c), s4, n4, x4q);
  __syncthreads();
}

// ---------------- K1: per-channel partial sum/min/max (regular loads) ----------------
__global__ __launch_bounds__(256) void k_p1(const float4* __restrict__ x4,
    float* __restrict__ psum, float* __restrict__ pmin, float* __restrict__ pmax) {
  const int c = blockIdx.x, s = blockIdx.y, t = threadIdx.x;
  const int B0 = (s * 16 * C_CH + c) * P4;
  float sum = 0.0f, mn = INFINITY, mx = -INFINITY;
  #pragma unroll 1
  for (int g = 0; g < 7; ++g) {
    float4 v[7];
    #pragma unroll
    for (int j = 0; j < 7; ++j) {
      const int u = t + 256 * (7 * g + j);
      v[j] = x4[B0 + (u / P4) * PLANE_STRIDE + (u % P4)];
    }
    #pragma unroll
    for (int j = 0; j < 7; ++j) {
      const float4 w = v[j];
      sum = __fadd_rn(sum, __fadd_rn(__fadd_rn(w.x, w.y), __fadd_rn(w.z, w.w)));
      mn = fminf(mn, fminf(fminf(w.x, w.y), fminf(w.z, w.w)));
      mx = fmaxf(mx, fmaxf(fmaxf(w.x, w.y), fmaxf(w.z, w.w)));
    }
  }
  #pragma unroll
  for (int m = 1; m <= 32; m <<= 1) {
    sum = __fadd_rn(sum, __shfl_xor(sum, m, 64));
    mn = fminf(mn, __shfl_xor(mn, m, 64));
    mx = fmaxf(mx, __shfl_xor(mx, m, 64));
  }
  __shared__ float red[12];
  const int w_ = t >> 6;
  if ((t & 63) == 0) { red[w_] = sum; red[4 + w_] = mn; red[8 + w_] = mx; }
  __syncthreads();
  if (t == 0) {
    const int idx = c * 4 + s;
    psum[idx] = __fadd_rn(__fadd_rn(__fadd_rn(red[0], red[1]), red[2]), red[3]);
    pmin[idx] = fminf(fminf(red[4], red[5]), fminf(red[6], red[7]));
    pmax[idx] = fmaxf(fmaxf(red[8], red[9]), fmaxf(red[10], red[11]));
  }
}

// ---------------- K2: S1 prologue + int sums + packed-k store (NT x loads) ----------------
__global__ __launch_bounds__(256) void k_p2(const natf4* __restrict__ x4,
    uint32_t* __restrict__ kq32,
    const float* __restrict__ psum, const float* __restrict__ pmin,
    const float* __restrict__ pmax, const float* __restrict__ run_mean,
    uint32_t* __restrict__ pk, uint32_t* __restrict__ pk2) {
  __shared__ float buf4[4];
  __shared__ float bc[1];
  const int c = blockIdx.x, s = blockIdx.y, t = threadIdx.x;
  S1Out o; s1_compute(psum, pmin, pmax, run_mean, buf4, o);
  if (t == c) bc[0] = o.meanc;
  __syncthreads();
  const float m_c = bc[0];
  const double rd = 1.0 / (double)o.s1;
  const float r2 = (float)rd;
  const float c2 = (float)((-(double)m_c - (double)o.n1) * rd);
  const int B0 = (s * 16 * C_CH + c) * P4;
  int sk = 0, sk2 = 0;   // per-thread exact: sk<=5e4, sk2<=1.27e7
  #pragma unroll 1
  for (int g = 0; g < 7; ++g) {
    natf4 v[7]; int idx[7];
    #pragma unroll
    for (int j = 0; j < 7; ++j) {
      const int u = t + 256 * (7 * g + j);
      idx[j] = B0 + (u / P4) * PLANE_STRIDE + (u % P4);
      v[j] = __builtin_nontemporal_load(&x4[idx[j]]);         // dead after read
    }
    #pragma unroll
    for (int j = 0; j < 7; ++j) {
      const natf4 w = v[j];
      const float vv[4] = {w.x, w.y, w.z, w.w};
      uint32_t acc = 0;
      #pragma unroll
      for (int e = 0; e < 4; ++e) {
        const uint32_t k = qlevel(vv[e], r2, c2, m_c, o.s1, o.n1, o.x1);
        sk += (int)k; sk2 += (int)(k * k);
        acc |= k << (8 * e);
      }
      kq32[idx[j]] = acc;                                     // 4B/lane coalesced, L3-allocate
    }
  }
  #pragma unroll
  for (int m = 1; m <= 32; m <<= 1) {   // wave sums: sk2 <= 8.2e8 fits int
    sk += __shfl_xor(sk, m, 64);
    sk2 += __shfl_xor(sk2, m, 64);
  }
  __shared__ uint32_t ired[8];
  const int w_ = t >> 6;
  if ((t & 63) == 0) { ired[w_] = (uint32_t)sk; ired[4 + w_] = (uint32_t)sk2; }
  __syncthreads();
  if (t == 0) {
    const int idx = c * 4 + s;
    pk[idx]  = ired[0] + ired[1] + ired[2] + ired[3];          // <=1.3e7
    pk2[idx] = ired[4] + ired[5] + ired[6] + ired[7];          // <=3.27e9, fits u32
  }
}

// ---------------- K3: S1+S2 prologue + y = lut[kq] (NT kq loads, NT y stores) ----------------
__global__ __launch_bounds__(256) void k_p3(const uint32_t* __restrict__ kq32,
    const float* __restrict__ psum, const float* __restrict__ pmin,
    const float* __restrict__ pmax, const uint32_t* __restrict__ pk,
    const uint32_t* __restrict__ pk2,
    const float* __restrict__ run_mean, const float* __restrict__ run_var,
    const float* __restrict__ weight, const float* __restrict__ bias,
    natf4* __restrict__ y4) {
  __shared__ float buf4[4];
  __shared__ float bc[4];
  __shared__ float lut[256];
  const int c = blockIdx.x, s = blockIdx.y, t = threadIdx.x;
  S1Out o; s1_compute(psum, pmin, pmax, run_mean, buf4, o);
  s2_and_lut(o, pk, pk2, run_var, weight, bias, buf4, bc, lut, c);
  const int B0 = (s * 16 * C_CH + c) * P4;
  #pragma unroll 1
  for (int g = 0; g < 7; ++g) {
    uint32_t kk[7]; int idx[7];
    #pragma unroll
    for (int j = 0; j < 7; ++j) {
      const int u = t + 256 * (7 * g + j);
      idx[j] = B0 + (u / P4) * PLANE_STRIDE + (u % P4);
      kk[j] = __builtin_nontemporal_load(&kq32[idx[j]]);      // read-once
    }
    #pragma unroll
    for (int j = 0; j < 7; ++j) {
      const uint32_t w = kk[j];
      natf4 out;
      out.x = lut[w & 255]; out.y = lut[(w >> 8) & 255];
      out.z = lut[(w >> 16) & 255]; out.w = lut[w >> 24];
      __builtin_nontemporal_store(out, &y4[idx[j]]);          // 16B/lane: full lines
    }
  }
}

extern "C" void kernel_launch(void* const* d_in, const int* in_sizes, int n_in,
                              void* d_out, int out_size, void* d_ws, size_t ws_size,
                              hipStream_t stream) {
  const float4* x4      = (const float4*)d_in[0];
  const float* weight   = (const float*)d_in[1];
  const float* bias     = (const float*)d_in[2];
  const float* run_mean = (const float*)d_in[3];
  const float* run_var  = (const float*)d_in[4];
  natf4* y4 = (natf4*)d_out;

  float* w = (float*)d_ws;
  float* psum = w;                       // bytes     0.. 4095
  float* pmin = w + 1024;                //        4096.. 8191
  float* pmax = w + 2048;                //        8192..12287
  uint32_t* pk  = (uint32_t*)(w + 3072); //       12288..16383
  uint32_t* pk2 = (uint32_t*)(w + 4096); //       16384..20479
  uint32_t* kq32 = (uint32_t*)((char*)d_ws + 32768);  // 51,380,224 bytes

  dim3 grid(C_CH, 4), blk(256);
  k_p1<<<grid, blk, 0, stream>>>(x4, psum, pmin, pmax);
  k_p2<<<grid, blk, 0, stream>>>((const natf4*)x4, kq32, psum, pmin, pmax,
                                 run_mean, pk, pk2);
  k_p3<<<grid, blk, 0, stream>>>(kq32, psum, pmin, pmax, pk, pk2,
                                 run_mean, run_var, weight, bias, y4);
}

// Round 11
// 128.002 us; speedup vs baseline: 1.0812x; 1.0812x over previous
//
#include <hip/hip_runtime.h>
#include <stdint.h>

// QuantizedBatchNorm (k=8 fake-quant, training forward), NCHW = [64,256,56,56] f32.
//
// 3-kernel schedule (deterministic, no atomics), grid 256ch x 4 splits x 256 thr:
//  K1: read x (regular loads -> L3-allocate) -> per-(c,s) partial {sum,min,max}
//  K2: prologue = redundant S1; main = read x (regular loads: L3-hot), fast fma
//      quant level k (exact __fdiv_rn fallback near floor boundaries), EXACT
//      integer {sum k, sum k^2}, pack 4 levels -> uint32, NT store kq (bypass
//      L3: keep x the ONLY L3 resident -> x stays cached across graph replays)
//  K3: prologue = S1+S2 (exact var from int sums -> per-channel y-LUT in LDS);
//      main = NT-load kq (it's in HBM, and a regular load would evict 51 MB of
//      x), y = lut[k] float4/lane, NT store y.
// Steady-state L3 = pure x (205.5 MB < 256 MB); HBM/replay ~ 307 MB.
// COALESCING RULE (round-6 lesson): lane i <-> slot i, unit stride across
// lanes, 16B/lane stores = full 64B lines (kq: 4B/lane x 64 = 256B/wave).
// All ref-visible elementwise math uses __f*_rn sequences identical to numpy.

#define C_CH 256
#define P4 784                 // float4 per plane (HW/4)
#define PLANE_STRIDE 200704    // float4 stride between planes at fixed c (256*784)
#define NHW_F 200704.0f
#define NHW_D 200704.0
#define TOLB 1e-3f

typedef float natf4 __attribute__((ext_vector_type(4)));

__device__ __forceinline__ float fq(float x, float sc, float qn, float qx) {
  if (sc == 0.0f) return x;                                   // range==0 passthrough
  float cs = __fsub_rn(fminf(fmaxf(x, qn), qx), qn);
  float f  = floorf(__fadd_rn(__fdiv_rn(cs, sc), 0.5f));
  return __fadd_rn(__fmul_rn(f, sc), qn);
}

__device__ __forceinline__ void qparams(float amax, float& sc, float& qn, float& qx) {
  sc = __fdiv_rn(__fmul_rn(2.0f, amax), 255.0f);
  qn = __fmul_rn(-128.0f, sc);                                // nzp = round(127.5) = 128
  qx = __fmul_rn(127.0f, sc);
}

__device__ __forceinline__ float block_max(float v, float* buf4) {
  #pragma unroll
  for (int m = 1; m <= 32; m <<= 1) v = fmaxf(v, __shfl_xor(v, m, 64));
  if ((threadIdx.x & 63) == 0) buf4[threadIdx.x >> 6] = v;
  __syncthreads();
  float r = fmaxf(fmaxf(buf4[0], buf4[1]), fmaxf(buf4[2], buf4[3]));
  __syncthreads();
  return r;
}

// Fast quant level: q ~= (x - m - n1)/s1 via fma; exact __fdiv_rn ref-sequence
// fallback when within TOLB of a floor boundary (|fast-true| <= ~1e-4 << TOLB).
__device__ __forceinline__ uint32_t qlevel(float xv, float r2, float c2,
    float m, float s1, float n1, float x1) {
  float q = fmaf(xv, r2, c2);
  q = fminf(fmaxf(q, 0.0f), 255.0f);
  const float qh = __fadd_rn(q, 0.5f);
  float fl = floorf(qh);
  const float d = __fsub_rn(qh, fl);
  if (__builtin_expect(fminf(d, __fsub_rn(1.0f, d)) < TOLB, 0)) {
    const float tt = __fsub_rn(xv, m);
    const float cs = __fsub_rn(fminf(fmaxf(tt, n1), x1), n1);
    fl = floorf(__fadd_rn(__fdiv_rn(cs, s1), 0.5f));
  }
  return (uint32_t)fl;                                        // in [0,255]
}

// Redundant S1 (thread t <-> channel t; identical in every block).
struct S1Out { float meanc, tmax, tmin, s1, n1, x1; };

__device__ __forceinline__ void s1_compute(const float* __restrict__ psum,
    const float* __restrict__ pmin, const float* __restrict__ pmax,
    const float* __restrict__ run_mean, float* buf4, S1Out& o) {
  const int t = threadIdx.x;
  float sum = __fadd_rn(__fadd_rn(__fadd_rn(psum[4*t], psum[4*t+1]), psum[4*t+2]), psum[4*t+3]);
  float mn = fminf(fminf(pmin[4*t], pmin[4*t+1]), fminf(pmin[4*t+2], pmin[4*t+3]));
  float mx = fmaxf(fmaxf(pmax[4*t], pmax[4*t+1]), fmaxf(pmax[4*t+2], pmax[4*t+3]));
  const float new_mean = __fdiv_rn(sum, NHW_F);
  const float mp = __fadd_rn(__fmul_rn(0.875f, run_mean[t]), __fmul_rn(0.125f, new_mean));
  const float am = block_max(fabsf(mp), buf4);
  float scm, qnm, qxm; qparams(am, scm, qnm, qxm);
  o.meanc = fq(mp, scm, qnm, qxm);
  o.tmax = __fsub_rn(mx, o.meanc);   // (x - mean_c) monotone in x: extremes attained
  o.tmin = __fsub_rn(mn, o.meanc);
  const float a1 = block_max(fmaxf(fabsf(o.tmax), fabsf(o.tmin)), buf4);
  qparams(a1, o.s1, o.n1, o.x1);
}

// S2 body (thread t <-> channel t): exact var from integer sums -> LUT.
__device__ __forceinline__ void s2_and_lut(const S1Out& o,
    const uint32_t* __restrict__ pk, const uint32_t* __restrict__ pk2,
    const float* __restrict__ run_var, const float* __restrict__ weight,
    const float* __restrict__ bias, float* buf4, float* bc, float* lut, int c) {
  const int t = threadIdx.x;
  // sum(ctr^2) = s1^2 * (sum k^2 - 256 sum k + 16384*N)   (exact integers)
  const unsigned long long ssq = (unsigned long long)pk2[4*t] + pk2[4*t+1]
                               + pk2[4*t+2] + pk2[4*t+3];
  const unsigned int skc = pk[4*t] + pk[4*t+1] + pk[4*t+2] + pk[4*t+3];
  const double s1d = (double)o.s1;
  const double sum_ctr2 = s1d * s1d *
      ((double)ssq - 256.0 * (double)skc + 16384.0 * NHW_D);
  const float new_var = (float)(sum_ctr2 / NHW_D);
  const float vp = __fadd_rn(__fmul_rn(0.875f, run_var[t]), __fmul_rn(0.125f, new_var));
  const float av = block_max(fabsf(vp), buf4);
  float scv, qnv, qxv; qparams(av, scv, qnv, qxv);
  const float varc = fq(vp, scv, qnv, qxv);
  const float dp = __fsqrt_rn(__fadd_rn(varc, 1e-5f));
  const float ad = block_max(fabsf(dp), buf4);
  float scd, qnd, qxd; qparams(ad, scd, qnd, qxd);
  const float idc = fq(dp, scd, qnd, qxd);
  const float ctrmax = fq(o.tmax, o.s1, o.n1, o.x1);
  const float ctrmin = fq(o.tmin, o.s1, o.n1, o.x1);
  const float xpmax = __fdiv_rn(ctrmax, idc);
  const float xpmin = __fdiv_rn(ctrmin, idc);
  const float a3 = block_max(fmaxf(fabsf(xpmax), fabsf(xpmin)), buf4);
  float s3, n3, x3; qparams(a3, s3, n3, x3);
  const float xnmax = fq(xpmax, s3, n3, x3);
  const float xnmin = fq(xpmin, s3, n3, x3);
  const float wv = weight[t];
  const float aw = block_max(fabsf(wv), buf4);
  float scw, qnw, qxw; qparams(aw, scw, qnw, qxw);
  const float qw = fq(wv, scw, qnw, qxw);
  const float bv = bias[t];
  const float ab = block_max(fabsf(bv), buf4);
  float scb, qnb, qxb; qparams(ab, scb, qnb, qxb);
  const float qb = fq(bv, scb, qnb, qxb);                     // bias==0 -> passthrough
  const float e1 = __fadd_rn(__fmul_rn(qw, xnmax), qb);
  const float e2 = __fadd_rn(__fmul_rn(qw, xnmin), qb);
  const float a4 = block_max(fmaxf(fabsf(e1), fabsf(e2)), buf4);
  float s4, n4, x4q; qparams(a4, s4, n4, x4q);
  if (t == c) { bc[0] = idc; bc[1] = qw; bc[2] = qb; }
  __syncthreads();
  const float idc_c = bc[0], qw_c = bc[1], qb_c = bc[2];
  const float ctr_t = __fadd_rn(__fmul_rn((float)t, o.s1), o.n1);
  const float xn_t = fq(__fdiv_rn(ctr_t, idc_c), s3, n3, x3);
  lut[t] = fq(__fadd_rn(__fmul_rn(qw_c, xn_t), qb_c), s4, n4, x4q);
  __syncthreads();
}

// ---------------- K1: per-channel partial sum/min/max (regular loads) ----------------
__global__ __launch_bounds__(256) void k_p1(const float4* __restrict__ x4,
    float* __restrict__ psum, float* __restrict__ pmin, float* __restrict__ pmax) {
  const int c = blockIdx.x, s = blockIdx.y, t = threadIdx.x;
  const int B0 = (s * 16 * C_CH + c) * P4;
  float sum = 0.0f, mn = INFINITY, mx = -INFINITY;
  #pragma unroll 1
  for (int g = 0; g < 7; ++g) {
    float4 v[7];
    #pragma unroll
    for (int j = 0; j < 7; ++j) {
      const int u = t + 256 * (7 * g + j);
      v[j] = x4[B0 + (u / P4) * PLANE_STRIDE + (u % P4)];
    }
    #pragma unroll
    for (int j = 0; j < 7; ++j) {
      const float4 w = v[j];
      sum = __fadd_rn(sum, __fadd_rn(__fadd_rn(w.x, w.y), __fadd_rn(w.z, w.w)));
      mn = fminf(mn, fminf(fminf(w.x, w.y), fminf(w.z, w.w)));
      mx = fmaxf(mx, fmaxf(fmaxf(w.x, w.y), fmaxf(w.z, w.w)));
    }
  }
  #pragma unroll
  for (int m = 1; m <= 32; m <<= 1) {
    sum = __fadd_rn(sum, __shfl_xor(sum, m, 64));
    mn = fminf(mn, __shfl_xor(mn, m, 64));
    mx = fmaxf(mx, __shfl_xor(mx, m, 64));
  }
  __shared__ float red[12];
  const int w_ = t >> 6;
  if ((t & 63) == 0) { red[w_] = sum; red[4 + w_] = mn; red[8 + w_] = mx; }
  __syncthreads();
  if (t == 0) {
    const int idx = c * 4 + s;
    psum[idx] = __fadd_rn(__fadd_rn(__fadd_rn(red[0], red[1]), red[2]), red[3]);
    pmin[idx] = fminf(fminf(red[4], red[5]), fminf(red[6], red[7]));
    pmax[idx] = fmaxf(fmaxf(red[8], red[9]), fmaxf(red[10], red[11]));
  }
}

// ---------------- K2: S1 prologue + int sums + NT packed-k store ----------------
__global__ __launch_bounds__(256) void k_p2(const float4* __restrict__ x4,
    uint32_t* __restrict__ kq32,
    const float* __restrict__ psum, const float* __restrict__ pmin,
    const float* __restrict__ pmax, const float* __restrict__ run_mean,
    uint32_t* __restrict__ pk, uint32_t* __restrict__ pk2) {
  __shared__ float buf4[4];
  __shared__ float bc[1];
  const int c = blockIdx.x, s = blockIdx.y, t = threadIdx.x;
  S1Out o; s1_compute(psum, pmin, pmax, run_mean, buf4, o);
  if (t == c) bc[0] = o.meanc;
  __syncthreads();
  const float m_c = bc[0];
  const double rd = 1.0 / (double)o.s1;
  const float r2 = (float)rd;
  const float c2 = (float)((-(double)m_c - (double)o.n1) * rd);
  const int B0 = (s * 16 * C_CH + c) * P4;
  int sk = 0, sk2 = 0;   // per-thread exact: sk<=5e4, sk2<=1.27e7
  #pragma unroll 1
  for (int g = 0; g < 7; ++g) {
    float4 v[7]; int idx[7];
    #pragma unroll
    for (int j = 0; j < 7; ++j) {
      const int u = t + 256 * (7 * g + j);
      idx[j] = B0 + (u / P4) * PLANE_STRIDE + (u % P4);
      v[j] = x4[idx[j]];                                      // regular: L3-hot
    }
    #pragma unroll
    for (int j = 0; j < 7; ++j) {
      const float4 w = v[j];
      const float vv[4] = {w.x, w.y, w.z, w.w};
      uint32_t acc = 0;
      #pragma unroll
      for (int e = 0; e < 4; ++e) {
        const uint32_t k = qlevel(vv[e], r2, c2, m_c, o.s1, o.n1, o.x1);
        sk += (int)k; sk2 += (int)(k * k);
        acc |= k << (8 * e);
      }
      __builtin_nontemporal_store(acc, &kq32[idx[j]]);        // bypass L3: keep x resident
    }
  }
  #pragma unroll
  for (int m = 1; m <= 32; m <<= 1) {   // wave sums: sk2 <= 8.2e8 fits int
    sk += __shfl_xor(sk, m, 64);
    sk2 += __shfl_xor(sk2, m, 64);
  }
  __shared__ uint32_t ired[8];
  const int w_ = t >> 6;
  if ((t & 63) == 0) { ired[w_] = (uint32_t)sk; ired[4 + w_] = (uint32_t)sk2; }
  __syncthreads();
  if (t == 0) {
    const int idx = c * 4 + s;
    pk[idx]  = ired[0] + ired[1] + ired[2] + ired[3];          // <=1.3e7
    pk2[idx] = ired[4] + ired[5] + ired[6] + ired[7];          // <=3.27e9, fits u32
  }
}

// ---------------- K3: S1+S2 prologue + y = lut[kq] (NT kq load, NT y store) ----------------
__global__ __launch_bounds__(256) void k_p3(const uint32_t* __restrict__ kq32,
    const float* __restrict__ psum, const float* __restrict__ pmin,
    const float* __restrict__ pmax, const uint32_t* __restrict__ pk,
    const uint32_t* __restrict__ pk2,
    const float* __restrict__ run_mean, const float* __restrict__ run_var,
    const float* __restrict__ weight, const float* __restrict__ bias,
    natf4* __restrict__ y4) {
  __shared__ float buf4[4];
  __shared__ float bc[4];
  __shared__ float lut[256];
  const int c = blockIdx.x, s = blockIdx.y, t = threadIdx.x;
  S1Out o; s1_compute(psum, pmin, pmax, run_mean, buf4, o);
  s2_and_lut(o, pk, pk2, run_var, weight, bias, buf4, bc, lut, c);
  const int B0 = (s * 16 * C_CH + c) * P4;
  #pragma unroll 1
  for (int g = 0; g < 7; ++g) {
    uint32_t kk[7]; int idx[7];
    #pragma unroll
    for (int j = 0; j < 7; ++j) {
      const int u = t + 256 * (7 * g + j);
      idx[j] = B0 + (u / P4) * PLANE_STRIDE + (u % P4);
      kk[j] = __builtin_nontemporal_load(&kq32[idx[j]]);      // kq is in HBM; don't evict x
    }
    #pragma unroll
    for (int j = 0; j < 7; ++j) {
      const uint32_t w = kk[j];
      natf4 out;
      out.x = lut[w & 255]; out.y = lut[(w >> 8) & 255];
      out.z = lut[(w >> 16) & 255]; out.w = lut[w >> 24];
      __builtin_nontemporal_store(out, &y4[idx[j]]);          // 16B/lane: full lines
    }
  }
}

extern "C" void kernel_launch(void* const* d_in, const int* in_sizes, int n_in,
                              void* d_out, int out_size, void* d_ws, size_t ws_size,
                              hipStream_t stream) {
  const float4* x4      = (const float4*)d_in[0];
  const float* weight   = (const float*)d_in[1];
  const float* bias     = (const float*)d_in[2];
  const float* run_mean = (const float*)d_in[3];
  const float* run_var  = (const float*)d_in[4];
  natf4* y4 = (natf4*)d_out;

  float* w = (float*)d_ws;
  float* psum = w;                       // bytes     0.. 4095
  float* pmin = w + 1024;                //        4096.. 8191
  float* pmax = w + 2048;                //        8192..12287
  uint32_t* pk  = (uint32_t*)(w + 3072); //       12288..16383
  uint32_t* pk2 = (uint32_t*)(w + 4096); //       16384..20479
  uint32_t* kq32 = (uint32_t*)((char*)d_ws + 32768);  // 51,380,224 bytes

  dim3 grid(C_CH, 4), blk(256);
  k_p1<<<grid, blk, 0, stream>>>(x4, psum, pmin, pmax);
  k_p2<<<grid, blk, 0, stream>>>(x4, kq32, psum, pmin, pmax, run_mean, pk, pk2);
  k_p3<<<grid, blk, 0, stream>>>(kq32, psum, pmin, pmax, pk, pk2,
                                 run_mean, run_var, weight, bias, y4);
}

// Round 12
// 117.951 us; speedup vs baseline: 1.1733x; 1.0852x over previous
//
#include <hip/hip_runtime.h>
#include <stdint.h>

// QuantizedBatchNorm (k=8 fake-quant, training forward), NCHW = [64,256,56,56] f32.
// BEST CONFIG (round 7, 117.6 us). Reverted after rounds 8-11 proved all further
// cache/occupancy steering null or negative:
//   zig-zag scan: null | 2x grid/occupancy: null | NT x loads: -21 us
//   NT kq store+load: -10 us  (kq L3 residency is load-bearing)
//
// 3-kernel schedule (deterministic, no atomics), grid 256ch x 4 splits x 256 thr:
//  K1: read x -> per-(c,s) partial {sum, min, max}
//  K2: prologue = redundant S1; main = read x (L3-assisted), fast fma quant
//      level k (exact __fdiv_rn fallback near floor boundaries), EXACT integer
//      {sum k, sum k^2}, pack 4 levels -> uint32, coalesced regular store
//      (51 MB, L3-allocating for K3)
//  K3: prologue = S1+S2 (exact var from int sums -> per-channel y-LUT in LDS);
//      main = read kq (L3-hot), y = lut[k] float4/lane, NT store y.
// COALESCING RULE (round-6 lesson): lane i <-> slot i, unit stride across
// lanes, 16B/lane stores = full 64B lines.
// All ref-visible elementwise math uses __f*_rn sequences identical to numpy.

#define C_CH 256
#define P4 784                 // float4 per plane (HW/4)
#define PLANE_STRIDE 200704    // float4 stride between planes at fixed c (256*784)
#define NHW_F 200704.0f
#define NHW_D 200704.0
#define TOLB 1e-3f

typedef float natf4 __attribute__((ext_vector_type(4)));

__device__ __forceinline__ float fq(float x, float sc, float qn, float qx) {
  if (sc == 0.0f) return x;                                   // range==0 passthrough
  float cs = __fsub_rn(fminf(fmaxf(x, qn), qx), qn);
  float f  = floorf(__fadd_rn(__fdiv_rn(cs, sc), 0.5f));
  return __fadd_rn(__fmul_rn(f, sc), qn);
}

__device__ __forceinline__ void qparams(float amax, float& sc, float& qn, float& qx) {
  sc = __fdiv_rn(__fmul_rn(2.0f, amax), 255.0f);
  qn = __fmul_rn(-128.0f, sc);                                // nzp = round(127.5) = 128
  qx = __fmul_rn(127.0f, sc);
}

__device__ __forceinline__ float block_max(float v, float* buf4) {
  #pragma unroll
  for (int m = 1; m <= 32; m <<= 1) v = fmaxf(v, __shfl_xor(v, m, 64));
  if ((threadIdx.x & 63) == 0) buf4[threadIdx.x >> 6] = v;
  __syncthreads();
  float r = fmaxf(fmaxf(buf4[0], buf4[1]), fmaxf(buf4[2], buf4[3]));
  __syncthreads();
  return r;
}

// Fast quant level: q ~= (x - m - n1)/s1 via fma; exact __fdiv_rn ref-sequence
// fallback when within TOLB of a floor boundary (|fast-true| <= ~1e-4 << TOLB).
__device__ __forceinline__ uint32_t qlevel(float xv, float r2, float c2,
    float m, float s1, float n1, float x1) {
  float q = fmaf(xv, r2, c2);
  q = fminf(fmaxf(q, 0.0f), 255.0f);
  const float qh = __fadd_rn(q, 0.5f);
  float fl = floorf(qh);
  const float d = __fsub_rn(qh, fl);
  if (__builtin_expect(fminf(d, __fsub_rn(1.0f, d)) < TOLB, 0)) {
    const float tt = __fsub_rn(xv, m);
    const float cs = __fsub_rn(fminf(fmaxf(tt, n1), x1), n1);
    fl = floorf(__fadd_rn(__fdiv_rn(cs, s1), 0.5f));
  }
  return (uint32_t)fl;                                        // in [0,255]
}

// Redundant S1 (thread t <-> channel t; identical in every block).
struct S1Out { float meanc, tmax, tmin, s1, n1, x1; };

__device__ __forceinline__ void s1_compute(const float* __restrict__ psum,
    const float* __restrict__ pmin, const float* __restrict__ pmax,
    const float* __restrict__ run_mean, float* buf4, S1Out& o) {
  const int t = threadIdx.x;
  float sum = __fadd_rn(__fadd_rn(__fadd_rn(psum[4*t], psum[4*t+1]), psum[4*t+2]), psum[4*t+3]);
  float mn = fminf(fminf(pmin[4*t], pmin[4*t+1]), fminf(pmin[4*t+2], pmin[4*t+3]));
  float mx = fmaxf(fmaxf(pmax[4*t], pmax[4*t+1]), fmaxf(pmax[4*t+2], pmax[4*t+3]));
  const float new_mean = __fdiv_rn(sum, NHW_F);
  const float mp = __fadd_rn(__fmul_rn(0.875f, run_mean[t]), __fmul_rn(0.125f, new_mean));
  const float am = block_max(fabsf(mp), buf4);
  float scm, qnm, qxm; qparams(am, scm, qnm, qxm);
  o.meanc = fq(mp, scm, qnm, qxm);
  o.tmax = __fsub_rn(mx, o.meanc);   // (x - mean_c) monotone in x: extremes attained
  o.tmin = __fsub_rn(mn, o.meanc);
  const float a1 = block_max(fmaxf(fabsf(o.tmax), fabsf(o.tmin)), buf4);
  qparams(a1, o.s1, o.n1, o.x1);
}

// S2 body (thread t <-> channel t): exact var from integer sums -> LUT.
__device__ __forceinline__ void s2_and_lut(const S1Out& o,
    const uint32_t* __restrict__ pk, const uint32_t* __restrict__ pk2,
    const float* __restrict__ run_var, const float* __restrict__ weight,
    const float* __restrict__ bias, float* buf4, float* bc, float* lut, int c) {
  const int t = threadIdx.x;
  // sum(ctr^2) = s1^2 * (sum k^2 - 256 sum k + 16384*N)   (exact integers)
  const unsigned long long ssq = (unsigned long long)pk2[4*t] + pk2[4*t+1]
                               + pk2[4*t+2] + pk2[4*t+3];
  const unsigned int skc = pk[4*t] + pk[4*t+1] + pk[4*t+2] + pk[4*t+3];
  const double s1d = (double)o.s1;
  const double sum_ctr2 = s1d * s1d *
      ((double)ssq - 256.0 * (double)skc + 16384.0 * NHW_D);
  const float new_var = (float)(sum_ctr2 / NHW_D);
  const float vp = __fadd_rn(__fmul_rn(0.875f, run_var[t]), __fmul_rn(0.125f, new_var));
  const float av = block_max(fabsf(vp), buf4);
  float scv, qnv, qxv; qparams(av, scv, qnv, qxv);
  const float varc = fq(vp, scv, qnv, qxv);
  const float dp = __fsqrt_rn(__fadd_rn(varc, 1e-5f));
  const float ad = block_max(fabsf(dp), buf4);
  float scd, qnd, qxd; qparams(ad, scd, qnd, qxd);
  const float idc = fq(dp, scd, qnd, qxd);
  const float ctrmax = fq(o.tmax, o.s1, o.n1, o.x1);
  const float ctrmin = fq(o.tmin, o.s1, o.n1, o.x1);
  const float xpmax = __fdiv_rn(ctrmax, idc);
  const float xpmin = __fdiv_rn(ctrmin, idc);
  const float a3 = block_max(fmaxf(fabsf(xpmax), fabsf(xpmin)), buf4);
  float s3, n3, x3; qparams(a3, s3, n3, x3);
  const float xnmax = fq(xpmax, s3, n3, x3);
  const float xnmin = fq(xpmin, s3, n3, x3);
  const float wv = weight[t];
  const float aw = block_max(fabsf(wv), buf4);
  float scw, qnw, qxw; qparams(aw, scw, qnw, qxw);
  const float qw = fq(wv, scw, qnw, qxw);
  const float bv = bias[t];
  const float ab = block_max(fabsf(bv), buf4);
  float scb, qnb, qxb; qparams(ab, scb, qnb, qxb);
  const float qb = fq(bv, scb, qnb, qxb);                     // bias==0 -> passthrough
  const float e1 = __fadd_rn(__fmul_rn(qw, xnmax), qb);
  const float e2 = __fadd_rn(__fmul_rn(qw, xnmin), qb);
  const float a4 = block_max(fmaxf(fabsf(e1), fabsf(e2)), buf4);
  float s4, n4, x4q; qparams(a4, s4, n4, x4q);
  if (t == c) { bc[0] = idc; bc[1] = qw; bc[2] = qb; }
  __syncthreads();
  const float idc_c = bc[0], qw_c = bc[1], qb_c = bc[2];
  const float ctr_t = __fadd_rn(__fmul_rn((float)t, o.s1), o.n1);
  const float xn_t = fq(__fdiv_rn(ctr_t, idc_c), s3, n3, x3);
  lut[t] = fq(__fadd_rn(__fmul_rn(qw_c, xn_t), qb_c), s4, n4, x4q);
  __syncthreads();
}

// ---------------- K1: per-channel partial sum/min/max ----------------
__global__ __launch_bounds__(256) void k_p1(const float4* __restrict__ x4,
    float* __restrict__ psum, float* __restrict__ pmin, float* __restrict__ pmax) {
  const int c = blockIdx.x, s = blockIdx.y, t = threadIdx.x;
  const int B0 = (s * 16 * C_CH + c) * P4;
  float sum = 0.0f, mn = INFINITY, mx = -INFINITY;
  #pragma unroll 1
  for (int g = 0; g < 7; ++g) {
    float4 v[7];
    #pragma unroll
    for (int j = 0; j < 7; ++j) {
      const int u = t + 256 * (7 * g + j);
      v[j] = x4[B0 + (u / P4) * PLANE_STRIDE + (u % P4)];
    }
    #pragma unroll
    for (int j = 0; j < 7; ++j) {
      const float4 w = v[j];
      sum = __fadd_rn(sum, __fadd_rn(__fadd_rn(w.x, w.y), __fadd_rn(w.z, w.w)));
      mn = fminf(mn, fminf(fminf(w.x, w.y), fminf(w.z, w.w)));
      mx = fmaxf(mx, fmaxf(fmaxf(w.x, w.y), fmaxf(w.z, w.w)));
    }
  }
  #pragma unroll
  for (int m = 1; m <= 32; m <<= 1) {
    sum = __fadd_rn(sum, __shfl_xor(sum, m, 64));
    mn = fminf(mn, __shfl_xor(mn, m, 64));
    mx = fmaxf(mx, __shfl_xor(mx, m, 64));
  }
  __shared__ float red[12];
  const int w_ = t >> 6;
  if ((t & 63) == 0) { red[w_] = sum; red[4 + w_] = mn; red[8 + w_] = mx; }
  __syncthreads();
  if (t == 0) {
    const int idx = c * 4 + s;
    psum[idx] = __fadd_rn(__fadd_rn(__fadd_rn(red[0], red[1]), red[2]), red[3]);
    pmin[idx] = fminf(fminf(red[4], red[5]), fminf(red[6], red[7]));
    pmax[idx] = fmaxf(fmaxf(red[8], red[9]), fmaxf(red[10], red[11]));
  }
}

// ---------------- K2: S1 prologue + int sums + packed-k coalesced store ----------------
__global__ __launch_bounds__(256) void k_p2(const float4* __restrict__ x4,
    uint32_t* __restrict__ kq32,
    const float* __restrict__ psum, const float* __restrict__ pmin,
    const float* __restrict__ pmax, const float* __restrict__ run_mean,
    uint32_t* __restrict__ pk, uint32_t* __restrict__ pk2) {
  __shared__ float buf4[4];
  __shared__ float bc[1];
  const int c = blockIdx.x, s = blockIdx.y, t = threadIdx.x;
  S1Out o; s1_compute(psum, pmin, pmax, run_mean, buf4, o);
  if (t == c) bc[0] = o.meanc;
  __syncthreads();
  const float m_c = bc[0];
  const double rd = 1.0 / (double)o.s1;
  const float r2 = (float)rd;
  const float c2 = (float)((-(double)m_c - (double)o.n1) * rd);
  const int B0 = (s * 16 * C_CH + c) * P4;
  int sk = 0, sk2 = 0;   // per-thread exact: sk<=5e4, sk2<=1.27e7
  #pragma unroll 1
  for (int g = 0; g < 7; ++g) {
    float4 v[7]; int idx[7];
    #pragma unroll
    for (int j = 0; j < 7; ++j) {
      const int u = t + 256 * (7 * g + j);
      idx[j] = B0 + (u / P4) * PLANE_STRIDE + (u % P4);
      v[j] = x4[idx[j]];                                      // 16B/lane coalesced
    }
    #pragma unroll
    for (int j = 0; j < 7; ++j) {
      const float4 w = v[j];
      const float vv[4] = {w.x, w.y, w.z, w.w};
      uint32_t acc = 0;
      #pragma unroll
      for (int e = 0; e < 4; ++e) {
        const uint32_t k = qlevel(vv[e], r2, c2, m_c, o.s1, o.n1, o.x1);
        sk += (int)k; sk2 += (int)(k * k);
        acc |= k << (8 * e);
      }
      kq32[idx[j]] = acc;                                     // 4B/lane coalesced
    }
  }
  #pragma unroll
  for (int m = 1; m <= 32; m <<= 1) {   // wave sums: sk2 <= 8.2e8 fits int
    sk += __shfl_xor(sk, m, 64);
    sk2 += __shfl_xor(sk2, m, 64);
  }
  __shared__ uint32_t ired[8];
  const int w_ = t >> 6;
  if ((t & 63) == 0) { ired[w_] = (uint32_t)sk; ired[4 + w_] = (uint32_t)sk2; }
  __syncthreads();
  if (t == 0) {
    const int idx = c * 4 + s;
    pk[idx]  = ired[0] + ired[1] + ired[2] + ired[3];          // <=1.3e7
    pk2[idx] = ired[4] + ired[5] + ired[6] + ired[7];          // <=3.27e9, fits u32
  }
}

// ---------------- K3: S1+S2 prologue + y = lut[kq], coalesced NT store ----------------
__global__ __launch_bounds__(256) void k_p3(const uint32_t* __restrict__ kq32,
    const float* __restrict__ psum, const float* __restrict__ pmin,
    const float* __restrict__ pmax, const uint32_t* __restrict__ pk,
    const uint32_t* __restrict__ pk2,
    const float* __restrict__ run_mean, const float* __restrict__ run_var,
    const float* __restrict__ weight, const float* __restrict__ bias,
    natf4* __restrict__ y4) {
  __shared__ float buf4[4];
  __shared__ float bc[4];
  __shared__ float lut[256];
  const int c = blockIdx.x, s = blockIdx.y, t = threadIdx.x;
  S1Out o; s1_compute(psum, pmin, pmax, run_mean, buf4, o);
  s2_and_lut(o, pk, pk2, run_var, weight, bias, buf4, bc, lut, c);
  const int B0 = (s * 16 * C_CH + c) * P4;
  #pragma unroll 1
  for (int g = 0; g < 7; ++g) {
    uint32_t kk[7]; int idx[7];
    #pragma unroll
    for (int j = 0; j < 7; ++j) {
      const int u = t + 256 * (7 * g + j);
      idx[j] = B0 + (u / P4) * PLANE_STRIDE + (u % P4);
      kk[j] = kq32[idx[j]];                                   // 4B/lane coalesced, L3-hot
    }
    #pragma unroll
    for (int j = 0; j < 7; ++j) {
      const uint32_t w = kk[j];
      natf4 out;
      out.x = lut[w & 255]; out.y = lut[(w >> 8) & 255];
      out.z = lut[(w >> 16) & 255]; out.w = lut[w >> 24];
      __builtin_nontemporal_store(out, &y4[idx[j]]);          // 16B/lane: full lines
    }
  }
}

extern "C" void kernel_launch(void* const* d_in, const int* in_sizes, int n_in,
                              void* d_out, int out_size, void* d_ws, size_t ws_size,
                              hipStream_t stream) {
  const float4* x4      = (const float4*)d_in[0];
  const float* weight   = (const float*)d_in[1];
  const float* bias     = (const float*)d_in[2];
  const float* run_mean = (const float*)d_in[3];
  const float* run_var  = (const float*)d_in[4];
  natf4* y4 = (natf4*)d_out;

  float* w = (float*)d_ws;
  float* psum = w;                       // bytes     0.. 4095
  float* pmin = w + 1024;                //        4096.. 8191
  float* pmax = w + 2048;                //        8192..12287
  uint32_t* pk  = (uint32_t*)(w + 3072); //       12288..16383
  uint32_t* pk2 = (uint32_t*)(w + 4096); //       16384..20479
  uint32_t* kq32 = (uint32_t*)((char*)d_ws + 32768);  // 51,380,224 bytes

  dim3 grid(C_CH, 4), blk(256);
  k_p1<<<grid, blk, 0, stream>>>(x4, psum, pmin, pmax);
  k_p2<<<grid, blk, 0, stream>>>(x4, kq32, psum, pmin, pmax, run_mean, pk, pk2);
  k_p3<<<grid, blk, 0, stream>>>(kq32, psum, pmin, pmax, pk, pk2,
                                 run_mean, run_var, weight, bias, y4);
}